// Round 1
// baseline (734.870 us; speedup 1.0000x reference)
//
#include <hip/hip_runtime.h>

// Problem constants (fixed by setup_inputs)
#define H_      12
#define DIM_    768
#define HD_     64
#define BATCH_  8
#define SEQ_    1024
#define NNZ_    8192
#define N3_     2304   // 3*DIM

typedef short sh8 __attribute__((ext_vector_type(8)));
typedef float f32x4 __attribute__((ext_vector_type(4)));

__device__ __forceinline__ unsigned short f2bf(float f) {
    unsigned u = __float_as_uint(f);
    u += 0x7fff + ((u >> 16) & 1);   // round-to-nearest-even
    return (unsigned short)(u >> 16);
}

// async global->LDS, 16B per lane; LDS dest = wave-uniform base + lane*16
__device__ __forceinline__ void glds16(const unsigned short* g, unsigned short* l) {
    __builtin_amdgcn_global_load_lds(
        (const __attribute__((address_space(1))) unsigned int*)g,
        (__attribute__((address_space(3))) unsigned int*)l, 16, 0, 0);
}

// Fused: cast hidden + W to bf16, build inverse permutation. One launch.
__global__ void prep(const float* __restrict__ hidden,
                     const float* __restrict__ W,
                     const int* __restrict__ indices,
                     unsigned short* __restrict__ Xbf,
                     unsigned short* __restrict__ Wbf,
                     int* __restrict__ inv) {
    const int XN4 = NNZ_ * DIM_ / 4;
    const int WN4 = N3_ * DIM_ / 4;
    int i = blockIdx.x * blockDim.x + threadIdx.x;
    if (i < XN4) {
        float4 f = ((const float4*)hidden)[i];
        ushort4 u;
        u.x = f2bf(f.x); u.y = f2bf(f.y); u.z = f2bf(f.z); u.w = f2bf(f.w);
        ((ushort4*)Xbf)[i] = u;
    } else if (i < XN4 + WN4) {
        int k = i - XN4;
        float4 f = ((const float4*)W)[k];
        ushort4 u;
        u.x = f2bf(f.x); u.y = f2bf(f.y); u.z = f2bf(f.z); u.w = f2bf(f.w);
        ((ushort4*)Wbf)[k] = u;
    }
    if (i < NNZ_) inv[indices[i]] = i;
}

// C = X @ W^T + b, scattered into qkv workspace via indices.
// Q,K planes: [b][h][s][d] bf16. V plane stored TRANSPOSED: [b][h][d][s] bf16
// (free here - epilogue stores are scalar either way; makes attn's PV
//  B-fragment reads 16B-contiguous in global).
#define BK 32
__launch_bounds__(256)
__global__ void qkv_gemm(const unsigned short* __restrict__ X,
                         const unsigned short* __restrict__ W,
                         const float* __restrict__ bqkv,
                         const int* __restrict__ indices,
                         unsigned short* __restrict__ qkvbf) {
    __shared__ __align__(16) unsigned short As[128 * BK];   // 8 KB, rows of 64B
    __shared__ __align__(16) unsigned short Bs[128 * BK];

    const int bm = blockIdx.x * 128;
    const int bn = blockIdx.y * 128;
    const int t = threadIdx.x;
    const int wave = t >> 6;
    const int lane = t & 63;
    const int l16 = lane & 15;
    const int quad = lane >> 4;
    const int wm = (wave & 1) * 64;
    const int wn = (wave >> 1) * 64;

    f32x4 acc[4][4];
    for (int i = 0; i < 4; i++)
        for (int j = 0; j < 4; j++)
            for (int r = 0; r < 4; r++) acc[i][j][r] = 0.f;

    // staging: wave w owns chunks 2w, 2w+1 (each chunk = 16 rows x 64B = 1KB)
    const int c0 = wave * 2;
    const int r0 = c0 * 16 + (lane >> 2);
    const int colA = (lane & 3) * 8;
    const unsigned short* gA0 = &X[(size_t)(bm + r0) * DIM_ + colA];
    const unsigned short* gA1 = &X[(size_t)(bm + r0 + 16) * DIM_ + colA];
    const unsigned short* gB0 = &W[(size_t)(bn + r0) * DIM_ + colA];
    const unsigned short* gB1 = &W[(size_t)(bn + r0 + 16) * DIM_ + colA];
    unsigned short* lA0 = &As[c0 * 512];
    unsigned short* lA1 = &As[c0 * 512 + 512];
    unsigned short* lB0 = &Bs[c0 * 512];
    unsigned short* lB1 = &Bs[c0 * 512 + 512];

    for (int kk = 0; kk < DIM_; kk += BK) {
        __syncthreads();               // previous iter's LDS reads done
        glds16(gA0 + kk, lA0);
        glds16(gA1 + kk, lA1);
        glds16(gB0 + kk, lB0);
        glds16(gB1 + kk, lB1);
        __syncthreads();               // drains vmcnt -> staged data visible

        sh8 af[4], wf[4];
        for (int i = 0; i < 4; i++)
            af[i] = *(const sh8*)&As[(wm + i * 16 + l16) * BK + quad * 8];
        for (int j = 0; j < 4; j++)
            wf[j] = *(const sh8*)&Bs[(wn + j * 16 + l16) * BK + quad * 8];
        for (int i = 0; i < 4; i++)
            for (int j = 0; j < 4; j++)
                acc[i][j] = __builtin_amdgcn_mfma_f32_16x16x32_bf16(af[i], wf[j], acc[i][j], 0, 0, 0);
    }

    const size_t plane = (size_t)BATCH_ * H_ * SEQ_ * HD_;
    for (int i = 0; i < 4; i++) {
        for (int r = 0; r < 4; r++) {
            int m = bm + wm + i * 16 + quad * 4 + r;
            int pos = indices[m];
            int b = pos >> 10;
            int s = pos & 1023;
            for (int j = 0; j < 4; j++) {
                int n = bn + wn + j * 16 + l16;
                float val = acc[i][j][r] + bqkv[n];
                int which = n / DIM_;
                int nn = n - which * DIM_;
                int hh = nn >> 6;
                int d = nn & 63;
                size_t off;
                if (which == 2)   // V: transposed [b][h][d][s]
                    off = 2 * plane + (((size_t)b * H_ + hh) * HD_ + d) * SEQ_ + s;
                else
                    off = (size_t)which * plane + (((size_t)b * H_ + hh) * SEQ_ + s) * HD_ + d;
                qkvbf[off] = f2bf(val);
            }
        }
    }
}

// Flash attention, deferred softmax (no online max: scores bounded ~|6|, fp32
// exp safe). Grid: (S/64, B*H), 4 waves; wave w owns q-rows [qt*64+w*16,+16).
//
// NO K/V LDS staging: K+V per (b,h) is 256 KB -> L2-resident across the 16
// q-tile blocks that share it (guide Common-mistake #7). K is [s][d] and V is
// pre-transposed [d][s], so MFMA B-fragments are 16B-contiguous in global:
// read them directly. This removes ALL barriers from the kt loop (the Ps
// bounce is intra-wave, lgkmcnt-ordered) and the 8-way-conflicted 64B-stride
// LDS panel reads; bias/K/V load latency now overlaps compute freely inside
// one barrier-less scheduling region.
#define LDP 72   // Ps row stride (shorts): 144B, 16B-aligned for b128 reads
__launch_bounds__(256)
__global__ void attn(const unsigned short* __restrict__ qkvbf,
                     const float* __restrict__ bias,
                     const int* __restrict__ inv,
                     float* __restrict__ out) {
    __shared__ __align__(16) unsigned short Ps[4][16 * LDP];    // per-wave P tile

    const int qt = blockIdx.x;     // 0..15
    const int bh = blockIdx.y;     // 0..95
    const int t = threadIdx.x;
    const int wave = t >> 6;
    const int lane = t & 63;
    const int l16 = lane & 15;
    const int quad = lane >> 4;

    const size_t plane = (size_t)BATCH_ * H_ * SEQ_ * HD_;
    const unsigned short* Q  = qkvbf + (size_t)bh * SEQ_ * HD_;
    const unsigned short* K  = Q + plane;
    const unsigned short* Vt = qkvbf + 2 * plane + (size_t)bh * HD_ * SEQ_;  // [d][s]

    const int q0 = qt * 64 + wave * 16;

    sh8 aq[2];
    for (int kk2 = 0; kk2 < 2; kk2++)
        aq[kk2] = *(const sh8*)&Q[(size_t)(q0 + l16) * HD_ + kk2 * 32 + quad * 8];

    float l_p[4] = {0.f, 0.f, 0.f, 0.f};
    f32x4 o[4];
    for (int j = 0; j < 4; j++)
        for (int r = 0; r < 4; r++) o[j][r] = 0.f;

    const float scale = 0.125f;   // 1/sqrt(64)
    const float* brow = bias + (size_t)bh * SEQ_ * SEQ_;

    // per-lane fragment base pointers (K rows / Vt rows are B-fragments)
    const unsigned short* Kf  = &K[(size_t)l16 * HD_ + quad * 8];       // + (k0+j*16)*HD_ + kk2*32
    const unsigned short* Vtf = &Vt[(size_t)(l16)*SEQ_ + quad * 8];     // + j*16*SEQ_ + k0 + kk2*32

    for (int kt = 0; kt < 16; kt++) {
        const int k0 = kt * 64;

        // K fragments straight from global (L2-hit): row k0+j*16+l16, hd-half kk2
        sh8 bk[2][4];
        for (int kk2 = 0; kk2 < 2; kk2++)
            for (int j = 0; j < 4; j++)
                bk[kk2][j] = *(const sh8*)&Kf[(size_t)(k0 + j * 16) * HD_ + kk2 * 32];

        // bias tile into registers (HBM; latency hides under QK^T)
        float bv[4][4];
        for (int j = 0; j < 4; j++)
            for (int r = 0; r < 4; r++)
                bv[j][r] = brow[(size_t)(q0 + quad * 4 + r) * SEQ_ + k0 + j * 16 + l16];

        // V fragments straight from global: d-row j*16+l16, keys k0+kk2*32+quad*8
        sh8 vv[2][4];
        for (int kk2 = 0; kk2 < 2; kk2++)
            for (int j = 0; j < 4; j++)
                vv[kk2][j] = *(const sh8*)&Vtf[(size_t)(j * 16) * SEQ_ + k0 + kk2 * 32];

        // S = Q K^T
        f32x4 sc[4];
        for (int j = 0; j < 4; j++)
            for (int r = 0; r < 4; r++) sc[j][r] = 0.f;
        for (int kk2 = 0; kk2 < 2; kk2++)
            for (int j = 0; j < 4; j++)
                sc[j] = __builtin_amdgcn_mfma_f32_16x16x32_bf16(aq[kk2], bk[kk2][j], sc[j], 0, 0, 0);

        // p = exp(s*scale + bias); accumulate per-lane l partials; P -> LDS
        for (int j = 0; j < 4; j++)
            for (int r = 0; r < 4; r++) {
                float p = __expf(sc[j][r] * scale + bv[j][r]);
                l_p[r] += p;
                Ps[wave][(quad * 4 + r) * LDP + j * 16 + l16] = f2bf(p);
            }

        // O += P V (Ps write->read is intra-wave, lgkmcnt-ordered; no barrier)
        for (int kk2 = 0; kk2 < 2; kk2++) {
            sh8 ap = *(const sh8*)&Ps[wave][l16 * LDP + kk2 * 32 + quad * 8];
            for (int j = 0; j < 4; j++)
                o[j] = __builtin_amdgcn_mfma_f32_16x16x32_bf16(ap, vv[kk2][j], o[j], 0, 0, 0);
        }
    }

    // final l reduction across the 16 lanes of each quad-row group
    float l_i[4];
    for (int r = 0; r < 4; r++) {
        float s0 = l_p[r];
        for (int off = 1; off < 16; off <<= 1)
            s0 += __shfl_xor(s0, off, 64);
        l_i[r] = s0;
    }

    // epilogue: normalize, gather via inv(indices), fp32 out
    const int b = bh / H_;
    const int hh = bh % H_;
    for (int r = 0; r < 4; r++) {
        int srow_q = q0 + quad * 4 + r;
        int pos = b * SEQ_ + srow_q;
        int i_out = inv[pos];
        float rl = 1.0f / l_i[r];
        for (int j = 0; j < 4; j++)
            out[(size_t)i_out * DIM_ + hh * HD_ + j * 16 + l16] = o[j][r] * rl;
    }
}

extern "C" void kernel_launch(void* const* d_in, const int* in_sizes, int n_in,
                              void* d_out, int out_size, void* d_ws, size_t ws_size,
                              hipStream_t stream) {
    const float* hidden  = (const float*)d_in[0];
    const int*   indices = (const int*)d_in[3];
    const float* bias    = (const float*)d_in[5];
    const float* Wqkv_w  = (const float*)d_in[7];
    const float* Wqkv_b  = (const float*)d_in[8];
    float* out = (float*)d_out;

    char* ws = (char*)d_ws;
    unsigned short* Xbf   = (unsigned short*)ws;                  // 12,582,912 B
    unsigned short* Wbf   = (unsigned short*)(ws + 12582912);     //  3,538,944 B
    unsigned short* qkvbf = (unsigned short*)(ws + 16121856);     // 37,748,736 B
    int* inv              = (int*)(ws + 53870592);                //     32,768 B (~54 MB total)

    const int XN4 = NNZ_ * DIM_ / 4;
    const int WN4 = N3_ * DIM_ / 4;
    prep<<<(XN4 + WN4 + 255) / 256, 256, 0, stream>>>(hidden, Wqkv_w, indices, Xbf, Wbf, inv);
    qkv_gemm<<<dim3(NNZ_ / 128, N3_ / 128), 256, 0, stream>>>(Xbf, Wbf, Wqkv_b, indices, qkvbf);
    attn<<<dim3(SEQ_ / 64, BATCH_ * H_), 256, 0, stream>>>(qkvbf, bias, inv, out);
}

// Round 2
// 705.187 us; speedup vs baseline: 1.0421x; 1.0421x over previous
//
#include <hip/hip_runtime.h>

// Problem constants (fixed by setup_inputs)
#define H_      12
#define DIM_    768
#define HD_     64
#define BATCH_  8
#define SEQ_    1024
#define NNZ_    8192
#define N3_     2304   // 3*DIM

typedef short sh8 __attribute__((ext_vector_type(8)));
typedef float f32x4 __attribute__((ext_vector_type(4)));

__device__ __forceinline__ unsigned short f2bf(float f) {
    unsigned u = __float_as_uint(f);
    u += 0x7fff + ((u >> 16) & 1);   // round-to-nearest-even
    return (unsigned short)(u >> 16);
}

// async global->LDS, 16B per lane; LDS dest = wave-uniform base + lane*16
__device__ __forceinline__ void glds16(const unsigned short* g, unsigned short* l) {
    __builtin_amdgcn_global_load_lds(
        (const __attribute__((address_space(1))) unsigned int*)g,
        (__attribute__((address_space(3))) unsigned int*)l, 16, 0, 0);
}

// Fused: cast hidden + W to bf16, build inverse permutation. One launch.
__global__ void prep(const float* __restrict__ hidden,
                     const float* __restrict__ W,
                     const int* __restrict__ indices,
                     unsigned short* __restrict__ Xbf,
                     unsigned short* __restrict__ Wbf,
                     int* __restrict__ inv) {
    const int XN4 = NNZ_ * DIM_ / 4;
    const int WN4 = N3_ * DIM_ / 4;
    int i = blockIdx.x * blockDim.x + threadIdx.x;
    if (i < XN4) {
        float4 f = ((const float4*)hidden)[i];
        ushort4 u;
        u.x = f2bf(f.x); u.y = f2bf(f.y); u.z = f2bf(f.z); u.w = f2bf(f.w);
        ((ushort4*)Xbf)[i] = u;
    } else if (i < XN4 + WN4) {
        int k = i - XN4;
        float4 f = ((const float4*)W)[k];
        ushort4 u;
        u.x = f2bf(f.x); u.y = f2bf(f.y); u.z = f2bf(f.z); u.w = f2bf(f.w);
        ((ushort4*)Wbf)[k] = u;
    }
    if (i < NNZ_) inv[indices[i]] = i;
}

// C = X @ W^T + b, scattered into qkv workspace via indices.
// Q,K planes: [b][h][s][d] bf16. V plane stored TRANSPOSED: [b][h][d][s] bf16
// (makes attn's PV B-fragment reads 16B-contiguous in global).
#define BK 32
__launch_bounds__(256)
__global__ void qkv_gemm(const unsigned short* __restrict__ X,
                         const unsigned short* __restrict__ W,
                         const float* __restrict__ bqkv,
                         const int* __restrict__ indices,
                         unsigned short* __restrict__ qkvbf) {
    __shared__ __align__(16) unsigned short As[128 * BK];   // 8 KB, rows of 64B
    __shared__ __align__(16) unsigned short Bs[128 * BK];

    const int bm = blockIdx.x * 128;
    const int bn = blockIdx.y * 128;
    const int t = threadIdx.x;
    const int wave = t >> 6;
    const int lane = t & 63;
    const int l16 = lane & 15;
    const int quad = lane >> 4;
    const int wm = (wave & 1) * 64;
    const int wn = (wave >> 1) * 64;

    f32x4 acc[4][4];
    for (int i = 0; i < 4; i++)
        for (int j = 0; j < 4; j++)
            for (int r = 0; r < 4; r++) acc[i][j][r] = 0.f;

    // staging: wave w owns chunks 2w, 2w+1 (each chunk = 16 rows x 64B = 1KB)
    const int c0 = wave * 2;
    const int r0 = c0 * 16 + (lane >> 2);
    const int colA = (lane & 3) * 8;
    const unsigned short* gA0 = &X[(size_t)(bm + r0) * DIM_ + colA];
    const unsigned short* gA1 = &X[(size_t)(bm + r0 + 16) * DIM_ + colA];
    const unsigned short* gB0 = &W[(size_t)(bn + r0) * DIM_ + colA];
    const unsigned short* gB1 = &W[(size_t)(bn + r0 + 16) * DIM_ + colA];
    unsigned short* lA0 = &As[c0 * 512];
    unsigned short* lA1 = &As[c0 * 512 + 512];
    unsigned short* lB0 = &Bs[c0 * 512];
    unsigned short* lB1 = &Bs[c0 * 512 + 512];

    for (int kk = 0; kk < DIM_; kk += BK) {
        __syncthreads();               // previous iter's LDS reads done
        glds16(gA0 + kk, lA0);
        glds16(gA1 + kk, lA1);
        glds16(gB0 + kk, lB0);
        glds16(gB1 + kk, lB1);
        __syncthreads();               // drains vmcnt -> staged data visible

        sh8 af[4], wf[4];
        for (int i = 0; i < 4; i++)
            af[i] = *(const sh8*)&As[(wm + i * 16 + l16) * BK + quad * 8];
        for (int j = 0; j < 4; j++)
            wf[j] = *(const sh8*)&Bs[(wn + j * 16 + l16) * BK + quad * 8];
        for (int i = 0; i < 4; i++)
            for (int j = 0; j < 4; j++)
                acc[i][j] = __builtin_amdgcn_mfma_f32_16x16x32_bf16(af[i], wf[j], acc[i][j], 0, 0, 0);
    }

    const size_t plane = (size_t)BATCH_ * H_ * SEQ_ * HD_;
    for (int i = 0; i < 4; i++) {
        for (int r = 0; r < 4; r++) {
            int m = bm + wm + i * 16 + quad * 4 + r;
            int pos = indices[m];
            int b = pos >> 10;
            int s = pos & 1023;
            for (int j = 0; j < 4; j++) {
                int n = bn + wn + j * 16 + l16;
                float val = acc[i][j][r] + bqkv[n];
                int which = n / DIM_;
                int nn = n - which * DIM_;
                int hh = nn >> 6;
                int d = nn & 63;
                size_t off;
                if (which == 2)   // V: transposed [b][h][d][s]
                    off = 2 * plane + (((size_t)b * H_ + hh) * HD_ + d) * SEQ_ + s;
                else
                    off = (size_t)which * plane + (((size_t)b * H_ + hh) * SEQ_ + s) * HD_ + d;
                qkvbf[off] = f2bf(val);
            }
        }
    }
}

// Flash attention, deferred softmax (no online max: scores bounded ~|6|, fp32
// exp safe). Grid: (S/64, B*H), 4 waves; wave w owns q-rows [qt*64+w*16,+16).
//
// K/V read direct from global (L2-resident: XCD-chunked swizzle gives each
// XCD 12 bh values = 3 MB < 4 MB L2). Latency-bound fix vs r1 (VGPR=52,
// compiler sank loads to uses -> serial round trips): __launch_bounds__(256,4)
// for 128-VGPR budget + explicit pipeline: bias (HBM, ~900cy) prefetched one
// kt iteration ahead; K frags issued then QK^T; V frags issued then hidden
// under exp. sched_barrier(0) pins the load clusters ahead of compute.
#define LDP 72   // Ps row stride (shorts): 144B, 16B-aligned for b128 reads
__launch_bounds__(256, 4)
__global__ void attn(const unsigned short* __restrict__ qkvbf,
                     const float* __restrict__ bias,
                     const int* __restrict__ inv,
                     float* __restrict__ out) {
    __shared__ __align__(16) unsigned short Ps[4][16 * LDP];    // per-wave P tile

    // XCD-chunked bijective swizzle: 1536 blocks, 8 XCDs, 192 blocks/XCD.
    // XCD c owns swz in [c*192, (c+1)*192) -> bh in [c*12, c*12+12).
    const int orig = blockIdx.y * gridDim.x + blockIdx.x;
    const int swz = (orig & 7) * 192 + (orig >> 3);
    const int qt = swz & 15;      // 0..15
    const int bh = swz >> 4;      // 0..95

    const int t = threadIdx.x;
    const int wave = t >> 6;
    const int lane = t & 63;
    const int l16 = lane & 15;
    const int quad = lane >> 4;

    const size_t plane = (size_t)BATCH_ * H_ * SEQ_ * HD_;
    const unsigned short* Q  = qkvbf + (size_t)bh * SEQ_ * HD_;
    const unsigned short* K  = Q + plane;
    const unsigned short* Vt = qkvbf + 2 * plane + (size_t)bh * HD_ * SEQ_;  // [d][s]

    const int q0 = qt * 64 + wave * 16;

    sh8 aq[2];
    for (int kk2 = 0; kk2 < 2; kk2++)
        aq[kk2] = *(const sh8*)&Q[(size_t)(q0 + l16) * HD_ + kk2 * 32 + quad * 8];

    float l_p[4] = {0.f, 0.f, 0.f, 0.f};
    f32x4 o[4];
    for (int j = 0; j < 4; j++)
        for (int r = 0; r < 4; r++) o[j][r] = 0.f;

    const float scale = 0.125f;   // 1/sqrt(64)
    // bias row base for this lane's 4 q-rows
    const float* brow = bias + (size_t)bh * SEQ_ * SEQ_ + (size_t)(q0 + quad * 4) * SEQ_ + l16;

    // per-lane fragment base pointers (K rows / Vt rows are B-fragments)
    const unsigned short* Kf  = &K[(size_t)l16 * HD_ + quad * 8];       // + (k0+j*16)*HD_ + kk2*32
    const unsigned short* Vtf = &Vt[(size_t)l16 * SEQ_ + quad * 8];     // + j*16*SEQ_ + k0 + kk2*32

    // prologue: bias tile for kt=0 (prefetched one iteration ahead thereafter)
    float bv[4][4];
    for (int j = 0; j < 4; j++)
        for (int r = 0; r < 4; r++)
            bv[j][r] = brow[(size_t)r * SEQ_ + j * 16];

    for (int kt = 0; kt < 16; kt++) {
        const int k0 = kt * 64;
        const int k0n = (k0 + 64) & 1023;   // wraparound: kt=15 prefetch is discarded

        // --- issue cluster 1: K fragments + NEXT iteration's bias ---
        sh8 bk[2][4];
        for (int kk2 = 0; kk2 < 2; kk2++)
            for (int j = 0; j < 4; j++)
                bk[kk2][j] = *(const sh8*)&Kf[(size_t)(k0 + j * 16) * HD_ + kk2 * 32];

        float bvn[4][4];
        for (int j = 0; j < 4; j++)
            for (int r = 0; r < 4; r++)
                bvn[j][r] = brow[(size_t)r * SEQ_ + k0n + j * 16];

        __builtin_amdgcn_sched_barrier(0);  // loads stay ahead of compute

        // S = Q K^T
        f32x4 sc[4];
        for (int j = 0; j < 4; j++)
            for (int r = 0; r < 4; r++) sc[j][r] = 0.f;
        for (int kk2 = 0; kk2 < 2; kk2++)
            for (int j = 0; j < 4; j++)
                sc[j] = __builtin_amdgcn_mfma_f32_16x16x32_bf16(aq[kk2], bk[kk2][j], sc[j], 0, 0, 0);

        // --- issue cluster 2: V fragments (latency hides under exp) ---
        sh8 vv[2][4];
        for (int kk2 = 0; kk2 < 2; kk2++)
            for (int j = 0; j < 4; j++)
                vv[kk2][j] = *(const sh8*)&Vtf[(size_t)(j * 16) * SEQ_ + k0 + kk2 * 32];

        __builtin_amdgcn_sched_barrier(0);

        // p = exp(s*scale + bias_prefetched); accumulate l partials; P -> LDS
        for (int j = 0; j < 4; j++)
            for (int r = 0; r < 4; r++) {
                float p = __expf(sc[j][r] * scale + bv[j][r]);
                l_p[r] += p;
                Ps[wave][(quad * 4 + r) * LDP + j * 16 + l16] = f2bf(p);
            }

        // O += P V (Ps write->read is intra-wave, lgkmcnt-ordered; no barrier)
        for (int kk2 = 0; kk2 < 2; kk2++) {
            sh8 ap = *(const sh8*)&Ps[wave][l16 * LDP + kk2 * 32 + quad * 8];
            for (int j = 0; j < 4; j++)
                o[j] = __builtin_amdgcn_mfma_f32_16x16x32_bf16(ap, vv[kk2][j], o[j], 0, 0, 0);
        }

        // rotate bias prefetch
        for (int j = 0; j < 4; j++)
            for (int r = 0; r < 4; r++) bv[j][r] = bvn[j][r];
    }

    // final l reduction across the 16 lanes of each quad-row group
    float l_i[4];
    for (int r = 0; r < 4; r++) {
        float s0 = l_p[r];
        for (int off = 1; off < 16; off <<= 1)
            s0 += __shfl_xor(s0, off, 64);
        l_i[r] = s0;
    }

    // epilogue: normalize, gather via inv(indices), fp32 out
    const int b = bh / H_;
    const int hh = bh % H_;
    for (int r = 0; r < 4; r++) {
        int srow_q = q0 + quad * 4 + r;
        int pos = b * SEQ_ + srow_q;
        int i_out = inv[pos];
        float rl = 1.0f / l_i[r];
        for (int j = 0; j < 4; j++)
            out[(size_t)i_out * DIM_ + hh * HD_ + j * 16 + l16] = o[j][r] * rl;
    }
}

extern "C" void kernel_launch(void* const* d_in, const int* in_sizes, int n_in,
                              void* d_out, int out_size, void* d_ws, size_t ws_size,
                              hipStream_t stream) {
    const float* hidden  = (const float*)d_in[0];
    const int*   indices = (const int*)d_in[3];
    const float* bias    = (const float*)d_in[5];
    const float* Wqkv_w  = (const float*)d_in[7];
    const float* Wqkv_b  = (const float*)d_in[8];
    float* out = (float*)d_out;

    char* ws = (char*)d_ws;
    unsigned short* Xbf   = (unsigned short*)ws;                  // 12,582,912 B
    unsigned short* Wbf   = (unsigned short*)(ws + 12582912);     //  3,538,944 B
    unsigned short* qkvbf = (unsigned short*)(ws + 16121856);     // 37,748,736 B
    int* inv              = (int*)(ws + 53870592);                //     32,768 B (~54 MB total)

    const int XN4 = NNZ_ * DIM_ / 4;
    const int WN4 = N3_ * DIM_ / 4;
    prep<<<(XN4 + WN4 + 255) / 256, 256, 0, stream>>>(hidden, Wqkv_w, indices, Xbf, Wbf, inv);
    qkv_gemm<<<dim3(NNZ_ / 128, N3_ / 128), 256, 0, stream>>>(Xbf, Wbf, Wqkv_b, indices, qkvbf);
    attn<<<dim3(SEQ_ / 64, BATCH_ * H_), 256, 0, stream>>>(qkvbf, bias, inv, out);
}

// Round 3
// 624.910 us; speedup vs baseline: 1.1760x; 1.1285x over previous
//
#include <hip/hip_runtime.h>

// Problem constants (fixed by setup_inputs)
#define H_      12
#define DIM_    768
#define HD_     64
#define BATCH_  8
#define SEQ_    1024
#define NNZ_    8192
#define N3_     2304   // 3*DIM

typedef short sh8 __attribute__((ext_vector_type(8)));
typedef float f32x4 __attribute__((ext_vector_type(4)));

__device__ __forceinline__ unsigned short f2bf(float f) {
    unsigned u = __float_as_uint(f);
    u += 0x7fff + ((u >> 16) & 1);   // round-to-nearest-even
    return (unsigned short)(u >> 16);
}

// async global->LDS, 16B per lane; LDS dest = wave-uniform base + lane*16
__device__ __forceinline__ void glds16(const unsigned short* g, unsigned short* l) {
    __builtin_amdgcn_global_load_lds(
        (const __attribute__((address_space(1))) unsigned int*)g,
        (__attribute__((address_space(3))) unsigned int*)l, 16, 0, 0);
}

// Fused: cast hidden + W to bf16, build inverse permutation. One launch.
__global__ void prep(const float* __restrict__ hidden,
                     const float* __restrict__ W,
                     const int* __restrict__ indices,
                     unsigned short* __restrict__ Xbf,
                     unsigned short* __restrict__ Wbf,
                     int* __restrict__ inv) {
    const int XN4 = NNZ_ * DIM_ / 4;
    const int WN4 = N3_ * DIM_ / 4;
    int i = blockIdx.x * blockDim.x + threadIdx.x;
    if (i < XN4) {
        float4 f = ((const float4*)hidden)[i];
        ushort4 u;
        u.x = f2bf(f.x); u.y = f2bf(f.y); u.z = f2bf(f.z); u.w = f2bf(f.w);
        ((ushort4*)Xbf)[i] = u;
    } else if (i < XN4 + WN4) {
        int k = i - XN4;
        float4 f = ((const float4*)W)[k];
        ushort4 u;
        u.x = f2bf(f.x); u.y = f2bf(f.y); u.z = f2bf(f.z); u.w = f2bf(f.w);
        ((ushort4*)Wbf)[k] = u;
    }
    if (i < NNZ_) inv[indices[i]] = i;
}

// C = X @ W^T + b, scattered into qkv workspace via indices.
// Q,K planes: [b][h][s][d] bf16. V plane stored TRANSPOSED: [b][h][d][s] bf16
// (makes attn's PV B-fragment reads 16B-contiguous).
#define BK 32
__launch_bounds__(256)
__global__ void qkv_gemm(const unsigned short* __restrict__ X,
                         const unsigned short* __restrict__ W,
                         const float* __restrict__ bqkv,
                         const int* __restrict__ indices,
                         unsigned short* __restrict__ qkvbf) {
    __shared__ __align__(16) unsigned short As[128 * BK];   // 8 KB, rows of 64B
    __shared__ __align__(16) unsigned short Bs[128 * BK];

    const int bm = blockIdx.x * 128;
    const int bn = blockIdx.y * 128;
    const int t = threadIdx.x;
    const int wave = t >> 6;
    const int lane = t & 63;
    const int l16 = lane & 15;
    const int quad = lane >> 4;
    const int wm = (wave & 1) * 64;
    const int wn = (wave >> 1) * 64;

    f32x4 acc[4][4];
    for (int i = 0; i < 4; i++)
        for (int j = 0; j < 4; j++)
            for (int r = 0; r < 4; r++) acc[i][j][r] = 0.f;

    // staging: wave w owns chunks 2w, 2w+1 (each chunk = 16 rows x 64B = 1KB)
    const int c0 = wave * 2;
    const int r0 = c0 * 16 + (lane >> 2);
    const int colA = (lane & 3) * 8;
    const unsigned short* gA0 = &X[(size_t)(bm + r0) * DIM_ + colA];
    const unsigned short* gA1 = &X[(size_t)(bm + r0 + 16) * DIM_ + colA];
    const unsigned short* gB0 = &W[(size_t)(bn + r0) * DIM_ + colA];
    const unsigned short* gB1 = &W[(size_t)(bn + r0 + 16) * DIM_ + colA];
    unsigned short* lA0 = &As[c0 * 512];
    unsigned short* lA1 = &As[c0 * 512 + 512];
    unsigned short* lB0 = &Bs[c0 * 512];
    unsigned short* lB1 = &Bs[c0 * 512 + 512];

    for (int kk = 0; kk < DIM_; kk += BK) {
        __syncthreads();               // previous iter's LDS reads done
        glds16(gA0 + kk, lA0);
        glds16(gA1 + kk, lA1);
        glds16(gB0 + kk, lB0);
        glds16(gB1 + kk, lB1);
        __syncthreads();               // drains vmcnt -> staged data visible

        sh8 af[4], wf[4];
        for (int i = 0; i < 4; i++)
            af[i] = *(const sh8*)&As[(wm + i * 16 + l16) * BK + quad * 8];
        for (int j = 0; j < 4; j++)
            wf[j] = *(const sh8*)&Bs[(wn + j * 16 + l16) * BK + quad * 8];
        for (int i = 0; i < 4; i++)
            for (int j = 0; j < 4; j++)
                acc[i][j] = __builtin_amdgcn_mfma_f32_16x16x32_bf16(af[i], wf[j], acc[i][j], 0, 0, 0);
    }

    const size_t plane = (size_t)BATCH_ * H_ * SEQ_ * HD_;
    for (int i = 0; i < 4; i++) {
        for (int r = 0; r < 4; r++) {
            int m = bm + wm + i * 16 + quad * 4 + r;
            int pos = indices[m];
            int b = pos >> 10;
            int s = pos & 1023;
            for (int j = 0; j < 4; j++) {
                int n = bn + wn + j * 16 + l16;
                float val = acc[i][j][r] + bqkv[n];
                int which = n / DIM_;
                int nn = n - which * DIM_;
                int hh = nn >> 6;
                int d = nn & 63;
                size_t off;
                if (which == 2)   // V: transposed [b][h][d][s]
                    off = 2 * plane + (((size_t)b * H_ + hh) * HD_ + d) * SEQ_ + s;
                else
                    off = (size_t)which * plane + (((size_t)b * H_ + hh) * SEQ_ + s) * HD_ + d;
                qkvbf[off] = f2bf(val);
            }
        }
    }
}

// Flash attention, deferred softmax. Grid: (S/64, B*H), 4 waves.
// v3: LDS-staged K/V (r0 structure) + fixes:
//  - 2-phase double-buffer, ONE barrier/iter: next tile's glds16 + bias
//    (float4) issued BEFORE compute; the barrier's vmcnt(0) drain waits on
//    loads that overlapped a full compute phase (T3 minimum pipeline).
//  - swapped QK^T (mfma(K,Q) - same fragments, free): k-axis lands on the
//    accumulator ROW axis -> bias tile = 4x float4 coalesced loads (was 16
//    scalar), P->LDS = 4x ushort4, l-sum = 1 scalar + 2 shuffles.
//  - panel XOR swizzle: 64B rows alias bank-period 128B -> 8 lanes/slot per
//    b128 phase. glds16 writes linearly, so swizzle = pre-swizzled GLOBAL
//    source slot (lane&3)^(row&3) + swizzled read slot quad^(l16&3).
//  - XCD-chunked swizzle: each XCD owns 12 bh -> K/V 3MB < 4MB L2.
#define LDP 72   // Ps row stride (shorts): 144B
__launch_bounds__(256, 3)
__global__ void attn(const unsigned short* __restrict__ qkvbf,
                     const float* __restrict__ bias,
                     const int* __restrict__ inv,
                     float* __restrict__ out) {
    __shared__ __align__(16) unsigned short Kp[2][2][64 * 32];  // [buf][hd-half][key*32]
    __shared__ __align__(16) unsigned short Vp[2][2][64 * 32];  // [buf][key-half][d*32]
    __shared__ __align__(16) unsigned short Ps[4][16 * LDP];    // per-wave P tile [q][k]

    // XCD-chunked bijective swizzle: 1536 blocks, XCD c owns bh [c*12, c*12+12)
    const int orig = blockIdx.y * gridDim.x + blockIdx.x;
    const int swz = (orig & 7) * 192 + (orig >> 3);
    const int qt = swz & 15;      // 0..15
    const int bh = swz >> 4;      // 0..95

    const int t = threadIdx.x;
    const int wave = t >> 6;
    const int lane = t & 63;
    const int l16 = lane & 15;
    const int quad = lane >> 4;
    const int qx = quad ^ (l16 & 3);   // swizzled read slot

    const size_t plane = (size_t)BATCH_ * H_ * SEQ_ * HD_;
    const unsigned short* Q  = qkvbf + (size_t)bh * SEQ_ * HD_;
    const unsigned short* K  = Q + plane;
    const unsigned short* Vt = qkvbf + 2 * plane + (size_t)bh * HD_ * SEQ_;  // [d][s]

    const int q0 = qt * 64 + wave * 16;

    // Q fragments (B-operand of swapped QK^T): Q[q0+l16][kk2*32+quad*8 ..+8]
    sh8 aq[2];
    for (int kk2 = 0; kk2 < 2; kk2++)
        aq[kk2] = *(const sh8*)&Q[(size_t)(q0 + l16) * HD_ + kk2 * 32 + quad * 8];

    float lsum = 0.f;
    f32x4 o[4];
    for (int j = 0; j < 4; j++)
        for (int r = 0; r < 4; r++) o[j][r] = 0.f;

    const float scale = 0.125f;   // 1/sqrt(64)
    // bias base: row q0+l16, k offset quad*4 (float4 covers acc rows r=0..3)
    const float* brow4 = bias + (size_t)bh * SEQ_ * SEQ_ + (size_t)(q0 + l16) * SEQ_ + quad * 4;

    // staging source: LDS linear dest (row=lane>>2, slot=lane&3) must hold
    // G[row][slot ^ (row&3)] -> pre-swizzle the global slot.
    const int lrow = wave * 16 + (lane >> 2);
    const int lslot = (lane & 3) ^ ((lane >> 2) & 3);
    const unsigned short* gK = &K[(size_t)lrow * HD_ + lslot * 8];
    const unsigned short* gV = &Vt[(size_t)lrow * SEQ_ + lslot * 8];
    unsigned short* lK0[2] = { &Kp[0][0][wave * 512], &Kp[0][1][wave * 512] };
    unsigned short* lK1[2] = { &Kp[1][0][wave * 512], &Kp[1][1][wave * 512] };
    unsigned short* lV0[2] = { &Vp[0][0][wave * 512], &Vp[0][1][wave * 512] };
    unsigned short* lV1[2] = { &Vp[1][0][wave * 512], &Vp[1][1][wave * 512] };

    // prologue: stage kt=0 into buf0, bias for kt=0
    glds16(gK,      lK0[0]);
    glds16(gK + 32, lK0[1]);
    glds16(gV,      lV0[0]);
    glds16(gV + 32, lV0[1]);
    float4 bv4[4];
    for (int j = 0; j < 4; j++)
        bv4[j] = *(const float4*)(brow4 + j * 16);
    __syncthreads();   // vmcnt drain: buf0 visible

    for (int kt = 0; kt < 16; kt++) {
        const int cur = kt & 1;

        // --- issue cluster: next K/V tile + next bias tile ---
        if (kt < 15) {
            const int k0n = (kt + 1) * 64;
            if (cur == 0) {
                glds16(gK + (size_t)k0n * HD_,      lK1[0]);
                glds16(gK + (size_t)k0n * HD_ + 32, lK1[1]);
                glds16(gV + k0n,      lV1[0]);
                glds16(gV + k0n + 32, lV1[1]);
            } else {
                glds16(gK + (size_t)k0n * HD_,      lK0[0]);
                glds16(gK + (size_t)k0n * HD_ + 32, lK0[1]);
                glds16(gV + k0n,      lV0[0]);
                glds16(gV + k0n + 32, lV0[1]);
            }
        }
        float4 bvn[4];
        {
            const int kb = ((kt + 1) & 15) * 64;
            for (int j = 0; j < 4; j++)
                bvn[j] = *(const float4*)(brow4 + kb + j * 16);
        }
        __builtin_amdgcn_sched_barrier(0);  // pin issue cluster ahead of compute

        // S^T = K Q  (A=K fragment, B=Q fragment): sc[j][r] = S[k0+j*16+quad*4+r][q0+l16]
        f32x4 sc[4];
        for (int j = 0; j < 4; j++)
            for (int r = 0; r < 4; r++) sc[j][r] = 0.f;
        for (int kk2 = 0; kk2 < 2; kk2++)
            for (int j = 0; j < 4; j++) {
                sh8 bk = *(const sh8*)&Kp[cur][kk2][(j * 16 + l16) * 32 + qx * 8];
                sc[j] = __builtin_amdgcn_mfma_f32_16x16x32_bf16(bk, aq[kk2], sc[j], 0, 0, 0);
            }

        // p = exp(s*scale + bias); P[q][k] -> LDS as ushort4; scalar l partial
        for (int j = 0; j < 4; j++) {
            float4 bb = bv4[j];
            float p0 = __expf(sc[j][0] * scale + bb.x);
            float p1 = __expf(sc[j][1] * scale + bb.y);
            float p2 = __expf(sc[j][2] * scale + bb.z);
            float p3 = __expf(sc[j][3] * scale + bb.w);
            lsum += (p0 + p1) + (p2 + p3);
            ushort4 u;
            u.x = f2bf(p0); u.y = f2bf(p1); u.z = f2bf(p2); u.w = f2bf(p3);
            *(ushort4*)&Ps[wave][l16 * LDP + j * 16 + quad * 4] = u;
        }

        // O += P V (Ps write->read intra-wave, lgkmcnt-ordered; no barrier)
        for (int kk2 = 0; kk2 < 2; kk2++) {
            sh8 ap = *(const sh8*)&Ps[wave][l16 * LDP + kk2 * 32 + quad * 8];
            for (int j = 0; j < 4; j++) {
                sh8 vvf = *(const sh8*)&Vp[cur][kk2][(j * 16 + l16) * 32 + qx * 8];
                o[j] = __builtin_amdgcn_mfma_f32_16x16x32_bf16(ap, vvf, o[j], 0, 0, 0);
            }
        }

        __syncthreads();   // single barrier: drains next-tile stage (overlapped)
        for (int j = 0; j < 4; j++) bv4[j] = bvn[j];
    }

    // l reduction: lane's lsum covers its quad's k-slice for q=q0+l16
    float s0 = lsum;
    s0 += __shfl_xor(s0, 16, 64);
    s0 += __shfl_xor(s0, 32, 64);
    // redistribute: o-rows are q = q0+quad*4+r; lane (quad*4+r) holds that q's l
    float rl[4];
    for (int r = 0; r < 4; r++)
        rl[r] = 1.0f / __shfl(s0, quad * 4 + r, 64);

    // epilogue: normalize, gather via inv(indices), fp32 out
    const int b = bh / H_;
    const int hh = bh % H_;
    for (int r = 0; r < 4; r++) {
        int srow_q = q0 + quad * 4 + r;
        int pos = b * SEQ_ + srow_q;
        int i_out = inv[pos];
        for (int j = 0; j < 4; j++)
            out[(size_t)i_out * DIM_ + hh * HD_ + j * 16 + l16] = o[j][r] * rl[r];
    }
}

extern "C" void kernel_launch(void* const* d_in, const int* in_sizes, int n_in,
                              void* d_out, int out_size, void* d_ws, size_t ws_size,
                              hipStream_t stream) {
    const float* hidden  = (const float*)d_in[0];
    const int*   indices = (const int*)d_in[3];
    const float* bias    = (const float*)d_in[5];
    const float* Wqkv_w  = (const float*)d_in[7];
    const float* Wqkv_b  = (const float*)d_in[8];
    float* out = (float*)d_out;

    char* ws = (char*)d_ws;
    unsigned short* Xbf   = (unsigned short*)ws;                  // 12,582,912 B
    unsigned short* Wbf   = (unsigned short*)(ws + 12582912);     //  3,538,944 B
    unsigned short* qkvbf = (unsigned short*)(ws + 16121856);     // 37,748,736 B
    int* inv              = (int*)(ws + 53870592);                //     32,768 B (~54 MB total)

    const int XN4 = NNZ_ * DIM_ / 4;
    const int WN4 = N3_ * DIM_ / 4;
    prep<<<(XN4 + WN4 + 255) / 256, 256, 0, stream>>>(hidden, Wqkv_w, indices, Xbf, Wbf, inv);
    qkv_gemm<<<dim3(NNZ_ / 128, N3_ / 128), 256, 0, stream>>>(Xbf, Wbf, Wqkv_b, indices, qkvbf);
    attn<<<dim3(SEQ_ / 64, BATCH_ * H_), 256, 0, stream>>>(qkvbf, bias, inv, out);
}